// Round 16
// baseline (183.010 us; speedup 1.0000x reference)
//
#include <hip/hip_runtime.h>

#define B_   8
#define C_   640
#define T_   1024
#define NH_  8
#define D_   80
#define DP_  96   // padded head dim for Q (12 x 16B slots); K is dense 80

typedef __attribute__((ext_vector_type(8))) short s16x8;
typedef __attribute__((ext_vector_type(4))) float f32x4;

__device__ __forceinline__ unsigned short f2b(float f) {
  unsigned u = __builtin_bit_cast(unsigned, f);
  u += 0x7FFFu + ((u >> 16) & 1u);
  return (unsigned short)(u >> 16);
}
__device__ __forceinline__ unsigned short f2bt(float f) {  // truncate (for P only)
  return (unsigned short)(__builtin_bit_cast(unsigned, f) >> 16);
}

__device__ __forceinline__ void gl_lds(const unsigned short* gp, unsigned short* lp) {
  __builtin_amdgcn_global_load_lds(
      (const __attribute__((address_space(1))) unsigned int*)gp,
      (__attribute__((address_space(3))) unsigned int*)lp, 16, 0, 0);
}

// ---------------- fused GroupNorm (blocks 0..255) + weight conv (blocks 256..655) ----------------
__global__ __launch_bounds__(256) void pre_kernel(
    const float* __restrict__ x, const float* __restrict__ w,
    const float* __restrict__ bias, unsigned short* __restrict__ xnt,
    const float* __restrict__ qw, const float* __restrict__ pw,
    unsigned short* __restrict__ oq, unsigned short* __restrict__ op) {
  const int tid = threadIdx.x;
  if (blockIdx.x >= 256) {  // ---- weight conversion ----
    const int NQ = 3 * C_ * C_ / 4, NP = C_ * C_ / 4;
    int i = (blockIdx.x - 256) * 256 + tid;
    for (; i < NQ + NP; i += 400 * 256) {
      const bool q = i < NQ;
      const float4 v = q ? ((const float4*)qw)[i] : ((const float4*)pw)[i - NQ];
      ushort4 o;
      o.x = f2b(v.x); o.y = f2b(v.y); o.z = f2b(v.z); o.w = f2b(v.w);
      if (q) ((ushort4*)oq)[i] = o; else ((ushort4*)op)[i - NQ] = o;
    }
    return;
  }
  // ---- GroupNorm -> xn^T [b][t][c] bf16 ----
  const int b = blockIdx.x >> 5, g = blockIdx.x & 31;
  const size_t base = ((size_t)b * C_ + g * 20) * T_;
  float s = 0.f, ss = 0.f;
  for (int i = tid; i < 20 * T_; i += 256) {
    const float v = x[base + i];
    s += v; ss += v * v;
  }
  #pragma unroll
  for (int mask = 1; mask < 64; mask <<= 1) {
    s += __shfl_xor(s, mask); ss += __shfl_xor(ss, mask);
  }
  __shared__ float red[2][4];
  if ((tid & 63) == 0) { red[0][tid >> 6] = s; red[1][tid >> 6] = ss; }
  __syncthreads();
  s  = red[0][0] + red[0][1] + red[0][2] + red[0][3];
  ss = red[1][0] + red[1][1] + red[1][2] + red[1][3];
  const float mu   = s * (1.f / 20480.f);
  const float var  = ss * (1.f / 20480.f) - mu * mu;
  const float rstd = rsqrtf(var + 1e-5f);
  float ac[20], bc[20];
  #pragma unroll
  for (int c = 0; c < 20; c++) {
    const float wc = w[g * 20 + c];
    ac[c] = wc * rstd;
    bc[c] = bias[g * 20 + c] - mu * ac[c];
  }
  for (int tc = tid; tc < T_; tc += 256) {
    const size_t xoff = base + tc;
    unsigned short* dst = xnt + ((size_t)b * T_ + tc) * C_ + g * 20;
    #pragma unroll
    for (int j = 0; j < 5; j++) {
      ushort4 o;
      o.x = f2b(x[xoff + (size_t)(j * 4 + 0) * T_] * ac[j * 4 + 0] + bc[j * 4 + 0]);
      o.y = f2b(x[xoff + (size_t)(j * 4 + 1) * T_] * ac[j * 4 + 1] + bc[j * 4 + 1]);
      o.z = f2b(x[xoff + (size_t)(j * 4 + 2) * T_] * ac[j * 4 + 2] + bc[j * 4 + 2]);
      o.w = f2b(x[xoff + (size_t)(j * 4 + 3) * T_] * ac[j * 4 + 3] + bc[j * 4 + 3]);
      *(ushort4*)(dst + j * 4) = o;
    }
  }
}

// ---------------- bf16 MFMA GEMM (round-14 validated; 3-buf rotation) ----------------
template <int MODE>
__global__ __launch_bounds__(MODE == 0 ? 512 : 256, 4) void gemm_mfma(
    const unsigned short* __restrict__ Wb, const unsigned short* __restrict__ Xb,
    const float* __restrict__ bias, const float* __restrict__ resid,
    unsigned short* __restrict__ qg, unsigned short* __restrict__ kg,
    unsigned short* __restrict__ vg, float* __restrict__ outf) {
  constexpr int AUSH = MODE == 0 ? 4096 : 2048;
  constexpr int BUFU = MODE == 0 ? 12288 : 6144;
  constexpr int MF   = MODE == 0 ? 4 : 2;
  constexpr int NIT  = C_ / 32;
  __shared__ __align__(16) char smem[MODE == 0 ? 73728 : 36864];
  unsigned short* const sm = (unsigned short*)smem;
  const int tid = threadIdx.x;
  const int lane = tid & 63, wvi = tid >> 6;
  const int wm = MODE == 0 ? (wvi >> 2) : (wvi >> 1);
  const int wn = MODE == 0 ? (wvi & 3) : (wvi & 1);
  const int rl = lane & 15, gq = lane >> 4;
  const int NM = (MODE == 0) ? 15 : 10;
  const int lid = blockIdx.x + NM * (blockIdx.y + (MODE == 0 ? 4 : 8) * blockIdx.z);
  const int bz = lid & 7;
  const int mn = lid >> 3;
  const int m0 = (mn % NM) * (MODE == 0 ? 128 : 64);
  const int n0 = (mn / NM) * (MODE == 0 ? 256 : 128);
  const unsigned short* Xbb = Xb + (size_t)bz * T_ * C_;

  f32x4 acc[MF][4];
  const f32x4 zed = {0.f, 0.f, 0.f, 0.f};
  #pragma unroll
  for (int i = 0; i < MF; i++)
    #pragma unroll
    for (int j = 0; j < 4; j++) acc[i][j] = zed;

  auto STAGE = [&](int buf, int k0) {
    unsigned short* const Ab = sm + buf * BUFU;
    unsigned short* const Bb = Ab + AUSH;
    if constexpr (MODE == 0) {
      #pragma unroll
      for (int it = 0; it < 3; it++) {
        const int chunk = it * 512 + tid;
        if (chunk < 512) {
          const int row = chunk >> 2;
          const int gs = (chunk & 3) ^ ((row >> 1) & 3);
          gl_lds(Wb + (size_t)(m0 + row) * C_ + k0 + gs * 8, Ab + (tid & ~63) * 8);
        } else {
          const int c2 = chunk - 512;
          const int row = c2 >> 2;
          const int gs = (c2 & 3) ^ ((row >> 1) & 3);
          gl_lds(Xbb + (size_t)(n0 + row) * C_ + k0 + gs * 8,
                 Bb + ((it - 1) * 512 + (tid & ~63)) * 8);
        }
      }
    } else {
      #pragma unroll
      for (int it = 0; it < 3; it++) {
        const int chunk = it * 256 + tid;
        if (it == 0) {
          const int row = chunk >> 2;
          const int gs = (chunk & 3) ^ ((row >> 1) & 3);
          gl_lds(Wb + (size_t)(m0 + row) * C_ + k0 + gs * 8, Ab + (tid & ~63) * 8);
        } else {
          const int c2 = chunk - 256;
          const int row = c2 >> 2;
          const int gs = (c2 & 3) ^ ((row >> 1) & 3);
          gl_lds(Xbb + (size_t)(n0 + row) * C_ + k0 + gs * 8,
                 Bb + ((it - 1) * 256 + (tid & ~63)) * 8);
        }
      }
    }
  };

  STAGE(0, 0);
  int cur = 0;
  for (int kk = 0; kk < NIT; kk++) {
    if (kk + 1 < NIT) {
      STAGE((cur + 1) % 3, (kk + 1) * 32);
      asm volatile("s_waitcnt vmcnt(3)" ::: "memory");
    } else {
      asm volatile("s_waitcnt vmcnt(0)" ::: "memory");
    }
    __builtin_amdgcn_s_barrier();
    __builtin_amdgcn_sched_barrier(0);
    const unsigned short* As = sm + cur * BUFU;
    const unsigned short* Bs = As + AUSH;
    s16x8 af[MF], bfr[4];
    #pragma unroll
    for (int mf = 0; mf < MF; mf++) {
      const int row = wm * (MF * 16) + mf * 16 + rl;
      const int sl = gq ^ ((row >> 1) & 3);
      af[mf] = *(const s16x8*)&As[row * 32 + sl * 8];
    }
    #pragma unroll
    for (int nf = 0; nf < 4; nf++) {
      const int row = wn * 64 + nf * 16 + rl;
      const int sl = gq ^ ((row >> 1) & 3);
      bfr[nf] = *(const s16x8*)&Bs[row * 32 + sl * 8];
    }
    __builtin_amdgcn_s_setprio(1);
    #pragma unroll
    for (int mf = 0; mf < MF; mf++)
      #pragma unroll
      for (int nf = 0; nf < 4; nf++)
        acc[mf][nf] = __builtin_amdgcn_mfma_f32_16x16x32_bf16(af[mf], bfr[nf],
                                                              acc[mf][nf], 0, 0, 0);
    __builtin_amdgcn_s_setprio(0);
    cur = (cur + 1) % 3;
  }
  __syncthreads();

  if constexpr (MODE == 1) {
    #pragma unroll
    for (int mf = 0; mf < MF; mf++)
      #pragma unroll
      for (int reg = 0; reg < 4; reg++) {
        const int o = m0 + wm * 32 + mf * 16 + gq * 4 + reg;
        const float bsv = bias[o];
        #pragma unroll
        for (int nf = 0; nf < 4; nf++) {
          const int tcol = n0 + wn * 64 + nf * 16 + rl;
          const size_t idx = ((size_t)bz * C_ + o) * T_ + tcol;
          outf[idx] = acc[mf][nf][reg] + bsv + resid[idx];
        }
      }
  } else {
    const bool isV = (m0 >= 2 * C_);
    if (isV) {
      #pragma unroll
      for (int mf = 0; mf < MF; mf++)
        #pragma unroll
        for (int reg = 0; reg < 4; reg++) {
          const int o = m0 + wm * 64 + mf * 16 + gq * 4 + reg;
          const float bsv = bias[o];
          const int od = o - 2 * C_;
          const int hh = od / 80, dd = od % 80;
          #pragma unroll
          for (int nf = 0; nf < 4; nf++) {
            const int t = n0 + wn * 64 + nf * 16 + rl;
            vg[(((size_t)bz * 8 + hh) * 80 + dd) * T_ + t] = f2b(acc[mf][nf][reg] + bsv);
          }
        }
    } else {
      const int which = (m0 >= C_) ? 1 : 0;
      const float osc = which ? 1.f : (0.11180339887498948f * 1.4426950408889634f);
      const int DSTR = which ? 80 : DP_;
      unsigned short* dst0 = which ? kg : qg;
      const int m0eff = m0 - which * C_;
      unsigned short* const L = sm + (wvi & 3) * (64 * 72);
      const int phase = wvi >> 2;
      #pragma unroll
      for (int ph = 0; ph < 2; ph++) {
        if (ph == 1) __syncthreads();
        if (phase == ph) {
          #pragma unroll
          for (int mf = 0; mf < MF; mf++)
            #pragma unroll
            for (int reg = 0; reg < 4; reg++) {
              const int o = m0 + wm * 64 + mf * 16 + gq * 4 + reg;
              const float bsv = bias[o];
              #pragma unroll
              for (int nf = 0; nf < 4; nf++)
                L[(nf * 16 + rl) * 72 + mf * 16 + gq * 4 + reg] =
                    f2b((acc[mf][nf][reg] + bsv) * osc);
            }
          #pragma unroll
          for (int it = 0; it < 8; it++) {
            const int idx = it * 64 + lane;
            const int tl = idx >> 3, seg = idx & 7;
            const uint4 v = *(const uint4*)&L[tl * 72 + seg * 8];
            const int oseg = m0eff + wm * 64 + seg * 8;
            const int hh = oseg / 80, d0 = oseg % 80;
            const int t = n0 + wn * 64 + tl;
            *(uint4*)&dst0[(((size_t)bz * 8 + hh) * T_ + t) * DSTR + d0] = v;
          }
          if (which == 0) {
            const int msBase = m0eff + wm * 64;
            const int h0 = msBase / 80, h1 = (msBase + 63) / 80;
            const uint4 z4 = make_uint4(0u, 0u, 0u, 0u);
            for (int hh2 = h0; hh2 <= h1; hh2++) {
              const int t = n0 + wn * 64 + lane;
              unsigned short* pd = dst0 + (((size_t)bz * 8 + hh2) * T_ + t) * DP_ + 80;
              *(uint4*)pd = z4;
              *(uint4*)(pd + 8) = z4;
            }
          }
        }
      }
    }
  }
}

// ---------------- flash attention: QBLK=64, 4 waves = 2 q-groups x 2 kv-groups ----------------
// grid (bh=64, qt=16) IDENTICAL to round 14 (same global access pattern / L2 behavior).
// Wave (wq=wvi>>1, wk=wvi&1): 32 q-rows x 32 keys. Per-wave LDS b128 reads/tile: 13 vs 24.
// kv-partials merged per block via the round-15-validated flash split-K identity.
// LDS = 40,960 B exactly -> 4 blocks/CU.
__global__ __launch_bounds__(256, 4) void flash_mfma(
    const unsigned short* __restrict__ Qg, const unsigned short* __restrict__ Kg,
    const unsigned short* __restrict__ Vg, unsigned short* __restrict__ at) {
  __shared__ __align__(16) char arena[40960];
  unsigned short* const Kdb = (unsigned short*)arena;            // 2 x 5120 ush (20,480 B)
  unsigned short* const Vs  = (unsigned short*)(arena + 20480);  // 5120 ush (10,240 B)
  unsigned short* const Ps  = (unsigned short*)(arena + 30720);  // 4 x 1280 ush (10,240 B)
  const int bh = blockIdx.x, qt = blockIdx.y;
  const int b = bh >> 3, h = bh & 7;
  const int tid = threadIdx.x, lane = tid & 63, wvi = tid >> 6;
  const int rl = lane & 15, gq = lane >> 4;
  const int wq = wvi >> 1, wk = wvi & 1;
  const unsigned short* Qt = Qg + ((size_t)bh * T_ + qt * 64) * DP_;
  const unsigned short* Kb = Kg + (size_t)bh * T_ * 80;
  const unsigned short* Vb = Vg + (size_t)bh * 80 * T_;

  {  // stage Q [12 slots][64 rows] into Kdb region (768 chunks = 3*256) -- round-14 code
    unsigned short* const qbase = (unsigned short*)Kdb;
    #pragma unroll
    for (int it = 0; it < 3; it++) {
      const int c = it * 256 + tid;
      const int row = c & 63, sl = c >> 6;
      gl_lds(Qt + (size_t)row * DP_ + sl * 8, qbase + (it * 256 + (tid & ~63)) * 8);
    }
  }
  __syncthreads();
  s16x8 qf[2][3];  // Q zero-padded at d>=80: slots 10,11 are zeros
  #pragma unroll
  for (int mfq = 0; mfq < 2; mfq++)
    #pragma unroll
    for (int ks = 0; ks < 3; ks++)
      qf[mfq][ks] = *(const s16x8*)((unsigned short*)Kdb +
                                    ((ks * 4 + gq) * 64 + wq * 32 + mfq * 16 + rl) * 8);
  __syncthreads();

  auto STAGE_K = [&](int buf, int ti) {  // byte-identical to round 14
    const int ko = ti * 64 * 80;
    unsigned short* const KL = Kdb + buf * 5120;
    #pragma unroll
    for (int it = 0; it < 3; it++) {
      if (it < 2 || tid < 128) {
        const int c = it * 256 + tid;
        const int row = c & 63, sl = c >> 6;
        gl_lds(Kb + ko + (size_t)row * 80 + sl * 8, KL + (it * 256 + (tid & ~63)) * 8);
      }
    }
  };
  auto STAGE_V = [&](int ti) {  // byte-identical to round 14
    const int vo = ti * 64;
    #pragma unroll
    for (int it = 0; it < 3; it++) {
      if (it < 2 || tid < 128) {
        const int c = it * 256 + tid;
        const int d = c % 80, s8 = (c / 80) * 8;
        gl_lds(Vb + (size_t)d * T_ + vo + s8, Vs + (it * 256 + (tid & ~63)) * 8);
      }
    }
  };

  const f32x4 zed = {0.f, 0.f, 0.f, 0.f};
  f32x4 o_[2][5];
  float m_[2][4], l_[2][4];  // per (mfq,reg); l_ lane-partial over this lane's keys
  #pragma unroll
  for (int q = 0; q < 2; q++) {
    #pragma unroll
    for (int i = 0; i < 5; i++) o_[q][i] = zed;
    #pragma unroll
    for (int i = 0; i < 4; i++) { m_[q][i] = -1e30f; l_[q][i] = 0.f; }
  }

  STAGE_K(0, 0);
  STAGE_V(0);
  __syncthreads();

  unsigned short* const Pw = Ps + wvi * 1280;  // [32 q][stride 40]
  for (int ti = 0; ti < 16; ti++) {
    const int cur = ti & 1;
    if (ti > 0) STAGE_V(ti);
    if (ti + 1 < 16) STAGE_K(cur ^ 1, ti + 1);
    const unsigned short* Kc = Kdb + cur * 5120;

    // S = Q K^T on this wave's 32 q-rows x 32 keys (keys wk*32 + nf*16 + rl)
    f32x4 s_[2][2];
    #pragma unroll
    for (int q = 0; q < 2; q++)
      #pragma unroll
      for (int nf = 0; nf < 2; nf++) s_[q][nf] = zed;
    __builtin_amdgcn_s_setprio(1);
    #pragma unroll
    for (int nf = 0; nf < 2; nf++)
      #pragma unroll
      for (int ks = 0; ks < 3; ks++) {
        const int sl = (ks < 2) ? (ks * 4 + gq) : (8 + (gq & 1));
        const s16x8 kf = *(const s16x8*)&Kc[(sl * 64 + wk * 32 + nf * 16 + rl) * 8];
        s_[0][nf] = __builtin_amdgcn_mfma_f32_16x16x32_bf16(qf[0][ks], kf, s_[0][nf], 0, 0, 0);
        s_[1][nf] = __builtin_amdgcn_mfma_f32_16x16x32_bf16(qf[1][ks], kf, s_[1][nf], 0, 0, 0);
      }
    __builtin_amdgcn_s_setprio(0);

    // online softmax per (mfq,reg): q-row = wq*32 + mfq*16 + gq*4 + reg
    #pragma unroll
    for (int mfq = 0; mfq < 2; mfq++)
      #pragma unroll
      for (int reg = 0; reg < 4; reg++) {
        const float v0 = s_[mfq][0][reg], v1 = s_[mfq][1][reg];
        const float mold = m_[mfq][reg];
        const float lmx = fmaxf(v0, v1);
        float p0, p1;
        if (__all(lmx <= mold + 8.f)) {
          p0 = __builtin_exp2f(v0 - mold); p1 = __builtin_exp2f(v1 - mold);
          l_[mfq][reg] += p0 + p1;
        } else {
          float mx = lmx;
          mx = fmaxf(mx, __shfl_xor(mx, 1)); mx = fmaxf(mx, __shfl_xor(mx, 2));
          mx = fmaxf(mx, __shfl_xor(mx, 4)); mx = fmaxf(mx, __shfl_xor(mx, 8));
          const float nm = fmaxf(mold, mx);
          const float corr = __builtin_exp2f(mold - nm);
          p0 = __builtin_exp2f(v0 - nm); p1 = __builtin_exp2f(v1 - nm);
          l_[mfq][reg] = l_[mfq][reg] * corr + (p0 + p1);
          m_[mfq][reg] = nm;
          #pragma unroll
          for (int df = 0; df < 5; df++) o_[mfq][df][reg] *= corr;
        }
        unsigned short* const pr = Pw + (mfq * 16 + gq * 4 + reg) * 40;
        pr[rl]      = f2bt(p0);
        pr[16 + rl] = f2bt(p1);
      }
    __syncthreads();  // drains V(ti) + K(ti+1); joins waves

    // O += P V^T (wave's 32 keys: V slots wk*4+gq); vf shared across mfq
    s16x8 pf[2];
    #pragma unroll
    for (int mfq = 0; mfq < 2; mfq++)
      pf[mfq] = *(const s16x8*)&Pw[(mfq * 16 + rl) * 40 + gq * 8];
    __builtin_amdgcn_s_setprio(1);
    #pragma unroll
    for (int df = 0; df < 5; df++) {
      const s16x8 vf = *(const s16x8*)&Vs[((wk * 4 + gq) * 80 + df * 16 + rl) * 8];
      o_[0][df] = __builtin_amdgcn_mfma_f32_16x16x32_bf16(pf[0], vf, o_[0][df], 0, 0, 0);
      o_[1][df] = __builtin_amdgcn_mfma_f32_16x16x32_bf16(pf[1], vf, o_[1][df], 0, 0, 0);
    }
    __builtin_amdgcn_s_setprio(0);
    __syncthreads();  // PV V-reads done before next STAGE_V overwrite
  }

  // ---- merge kv-split partials: wave (wq,1) -> wave (wq,0) (round-15-validated) ----
  __syncthreads();  // all PV done; arena free
  f32x4* const Ob  = (f32x4*)arena;             // 5 x 128 f32x4 = 10,240 B (Kdb region)
  float*  const MLb = (float*)(arena + 20480);  // 128 x 8 f32 = 4,096 B (Vs region)
  const int pid = wq * 64 + lane;               // partner-pair index 0..127
  #pragma unroll
  for (int mfq = 0; mfq < 2; mfq++) {
    if (wk == 1) {
      *(f32x4*)&MLb[pid * 8]     = *(f32x4*)&m_[mfq][0];
      *(f32x4*)&MLb[pid * 8 + 4] = *(f32x4*)&l_[mfq][0];
      #pragma unroll
      for (int df = 0; df < 5; df++) Ob[df * 128 + pid] = o_[mfq][df];
    }
    __syncthreads();
    if (wk == 0) {
      const f32x4 m1 = *(const f32x4*)&MLb[pid * 8];
      const f32x4 l1 = *(const f32x4*)&MLb[pid * 8 + 4];
      f32x4 s0, s1;
      #pragma unroll
      for (int reg = 0; reg < 4; reg++) {
        const float nm = fmaxf(m_[mfq][reg], m1[reg]);
        s0[reg] = __builtin_exp2f(m_[mfq][reg] - nm);
        s1[reg] = __builtin_exp2f(m1[reg] - nm);
        l_[mfq][reg] = l_[mfq][reg] * s0[reg] + l1[reg] * s1[reg];
      }
      #pragma unroll
      for (int df = 0; df < 5; df++) {
        const f32x4 o1 = Ob[df * 128 + pid];
        #pragma unroll
        for (int reg = 0; reg < 4; reg++)
          o_[mfq][df][reg] = o_[mfq][df][reg] * s0[reg] + o1[reg] * s1[reg];
      }
    }
    __syncthreads();  // before next mfq reuses the arena
  }

  if (wk == 0) {
    #pragma unroll
    for (int mfq = 0; mfq < 2; mfq++)
      #pragma unroll
      for (int reg = 0; reg < 4; reg++) {
        float l = l_[mfq][reg];  // reduce lane-partials over rl (keys)
        l += __shfl_xor(l, 1); l += __shfl_xor(l, 2);
        l += __shfl_xor(l, 4); l += __shfl_xor(l, 8);
        const float inv = 1.f / l;
        const int t = qt * 64 + wq * 32 + mfq * 16 + gq * 4 + reg;
        #pragma unroll
        for (int df = 0; df < 5; df++)
          at[((size_t)b * T_ + t) * C_ + h * 80 + df * 16 + rl] =
              f2b(o_[mfq][df][reg] * inv);
      }
  }
}

extern "C" void kernel_launch(void* const* d_in, const int* in_sizes, int n_in,
                              void* d_out, int out_size, void* d_ws, size_t ws_size,
                              hipStream_t stream) {
  const float* x      = (const float*)d_in[0];
  const float* norm_w = (const float*)d_in[1];
  const float* norm_b = (const float*)d_in[2];
  const float* qkv_w  = (const float*)d_in[3];
  const float* qkv_b  = (const float*)d_in[4];
  const float* proj_w = (const float*)d_in[5];
  const float* proj_b = (const float*)d_in[6];
  float* out = (float*)d_out;

  char* ws = (char*)d_ws;
  const size_t SEG  = (size_t)B_ * T_ * C_ * 2;          // 10,485,760 B
  const size_t SEGP = (size_t)B_ * NH_ * T_ * DP_ * 2;   // 12,582,912 B (Q only)
  unsigned short* xnt = (unsigned short*)ws;
  unsigned short* Qb  = (unsigned short*)(ws + SEG);
  unsigned short* Kb2 = (unsigned short*)(ws + SEG + SEGP);          // dense 80
  unsigned short* Vb2 = (unsigned short*)(ws + 2 * SEG + SEGP);
  unsigned short* atb = (unsigned short*)(ws + 3 * SEG + SEGP);
  unsigned short* wq  = (unsigned short*)(ws + 4 * SEG + SEGP);
  unsigned short* wp  = (unsigned short*)(ws + 4 * SEG + SEGP + (size_t)3 * C_ * C_ * 2);

  pre_kernel<<<dim3(656), dim3(256), 0, stream>>>(x, norm_w, norm_b, xnt,
                                                  qkv_w, proj_w, wq, wp);
  gemm_mfma<0><<<dim3(15, 4, 8), dim3(512), 0, stream>>>(wq, xnt, qkv_b, nullptr,
                                                         Qb, Kb2, Vb2, nullptr);
  flash_mfma<<<dim3(64, 16), dim3(256), 0, stream>>>(Qb, Kb2, Vb2, atb);
  gemm_mfma<1><<<dim3(10, 8, 8), dim3(256), 0, stream>>>(wp, atb, proj_b, x,
                                                         nullptr, nullptr, nullptr, out);
}

// Round 17
// 170.723 us; speedup vs baseline: 1.0720x; 1.0720x over previous
//
#include <hip/hip_runtime.h>

#define B_   8
#define C_   640
#define T_   1024
#define NH_  8
#define D_   80
#define DP_  96   // padded head dim for Q (12 x 16B slots); K is dense 80

typedef __attribute__((ext_vector_type(8))) short s16x8;
typedef __attribute__((ext_vector_type(4))) float f32x4;

__device__ __forceinline__ unsigned short f2b(float f) {
  unsigned u = __builtin_bit_cast(unsigned, f);
  u += 0x7FFFu + ((u >> 16) & 1u);
  return (unsigned short)(u >> 16);
}
__device__ __forceinline__ unsigned short f2bt(float f) {  // truncate (for P only)
  return (unsigned short)(__builtin_bit_cast(unsigned, f) >> 16);
}

__device__ __forceinline__ void gl_lds(const unsigned short* gp, unsigned short* lp) {
  __builtin_amdgcn_global_load_lds(
      (const __attribute__((address_space(1))) unsigned int*)gp,
      (__attribute__((address_space(3))) unsigned int*)lp, 16, 0, 0);
}

// ---------------- fused GroupNorm (blocks 0..255) + weight conv (blocks 256..655) ----------------
__global__ __launch_bounds__(256) void pre_kernel(
    const float* __restrict__ x, const float* __restrict__ w,
    const float* __restrict__ bias, unsigned short* __restrict__ xnt,
    const float* __restrict__ qw, const float* __restrict__ pw,
    unsigned short* __restrict__ oq, unsigned short* __restrict__ op) {
  const int tid = threadIdx.x;
  if (blockIdx.x >= 256) {  // ---- weight conversion ----
    const int NQ = 3 * C_ * C_ / 4, NP = C_ * C_ / 4;
    int i = (blockIdx.x - 256) * 256 + tid;
    for (; i < NQ + NP; i += 400 * 256) {
      const bool q = i < NQ;
      const float4 v = q ? ((const float4*)qw)[i] : ((const float4*)pw)[i - NQ];
      ushort4 o;
      o.x = f2b(v.x); o.y = f2b(v.y); o.z = f2b(v.z); o.w = f2b(v.w);
      if (q) ((ushort4*)oq)[i] = o; else ((ushort4*)op)[i - NQ] = o;
    }
    return;
  }
  // ---- GroupNorm -> xn^T [b][t][c] bf16 ----
  const int b = blockIdx.x >> 5, g = blockIdx.x & 31;
  const size_t base = ((size_t)b * C_ + g * 20) * T_;
  float s = 0.f, ss = 0.f;
  for (int i = tid; i < 20 * T_; i += 256) {
    const float v = x[base + i];
    s += v; ss += v * v;
  }
  #pragma unroll
  for (int mask = 1; mask < 64; mask <<= 1) {
    s += __shfl_xor(s, mask); ss += __shfl_xor(ss, mask);
  }
  __shared__ float red[2][4];
  if ((tid & 63) == 0) { red[0][tid >> 6] = s; red[1][tid >> 6] = ss; }
  __syncthreads();
  s  = red[0][0] + red[0][1] + red[0][2] + red[0][3];
  ss = red[1][0] + red[1][1] + red[1][2] + red[1][3];
  const float mu   = s * (1.f / 20480.f);
  const float var  = ss * (1.f / 20480.f) - mu * mu;
  const float rstd = rsqrtf(var + 1e-5f);
  float ac[20], bc[20];
  #pragma unroll
  for (int c = 0; c < 20; c++) {
    const float wc = w[g * 20 + c];
    ac[c] = wc * rstd;
    bc[c] = bias[g * 20 + c] - mu * ac[c];
  }
  for (int tc = tid; tc < T_; tc += 256) {
    const size_t xoff = base + tc;
    unsigned short* dst = xnt + ((size_t)b * T_ + tc) * C_ + g * 20;
    #pragma unroll
    for (int j = 0; j < 5; j++) {
      ushort4 o;
      o.x = f2b(x[xoff + (size_t)(j * 4 + 0) * T_] * ac[j * 4 + 0] + bc[j * 4 + 0]);
      o.y = f2b(x[xoff + (size_t)(j * 4 + 1) * T_] * ac[j * 4 + 1] + bc[j * 4 + 1]);
      o.z = f2b(x[xoff + (size_t)(j * 4 + 2) * T_] * ac[j * 4 + 2] + bc[j * 4 + 2]);
      o.w = f2b(x[xoff + (size_t)(j * 4 + 3) * T_] * ac[j * 4 + 3] + bc[j * 4 + 3]);
      *(ushort4*)(dst + j * 4) = o;
    }
  }
}

// ---------------- bf16 MFMA GEMM (round-14 validated; 3-buf rotation) ----------------
template <int MODE>
__global__ __launch_bounds__(MODE == 0 ? 512 : 256, 4) void gemm_mfma(
    const unsigned short* __restrict__ Wb, const unsigned short* __restrict__ Xb,
    const float* __restrict__ bias, const float* __restrict__ resid,
    unsigned short* __restrict__ qg, unsigned short* __restrict__ kg,
    unsigned short* __restrict__ vg, float* __restrict__ outf) {
  constexpr int AUSH = MODE == 0 ? 4096 : 2048;
  constexpr int BUFU = MODE == 0 ? 12288 : 6144;
  constexpr int MF   = MODE == 0 ? 4 : 2;
  constexpr int NIT  = C_ / 32;
  __shared__ __align__(16) char smem[MODE == 0 ? 73728 : 36864];
  unsigned short* const sm = (unsigned short*)smem;
  const int tid = threadIdx.x;
  const int lane = tid & 63, wvi = tid >> 6;
  const int wm = MODE == 0 ? (wvi >> 2) : (wvi >> 1);
  const int wn = MODE == 0 ? (wvi & 3) : (wvi & 1);
  const int rl = lane & 15, gq = lane >> 4;
  const int NM = (MODE == 0) ? 15 : 10;
  const int lid = blockIdx.x + NM * (blockIdx.y + (MODE == 0 ? 4 : 8) * blockIdx.z);
  const int bz = lid & 7;
  const int mn = lid >> 3;
  const int m0 = (mn % NM) * (MODE == 0 ? 128 : 64);
  const int n0 = (mn / NM) * (MODE == 0 ? 256 : 128);
  const unsigned short* Xbb = Xb + (size_t)bz * T_ * C_;

  f32x4 acc[MF][4];
  const f32x4 zed = {0.f, 0.f, 0.f, 0.f};
  #pragma unroll
  for (int i = 0; i < MF; i++)
    #pragma unroll
    for (int j = 0; j < 4; j++) acc[i][j] = zed;

  auto STAGE = [&](int buf, int k0) {
    unsigned short* const Ab = sm + buf * BUFU;
    unsigned short* const Bb = Ab + AUSH;
    if constexpr (MODE == 0) {
      #pragma unroll
      for (int it = 0; it < 3; it++) {
        const int chunk = it * 512 + tid;
        if (chunk < 512) {
          const int row = chunk >> 2;
          const int gs = (chunk & 3) ^ ((row >> 1) & 3);
          gl_lds(Wb + (size_t)(m0 + row) * C_ + k0 + gs * 8, Ab + (tid & ~63) * 8);
        } else {
          const int c2 = chunk - 512;
          const int row = c2 >> 2;
          const int gs = (c2 & 3) ^ ((row >> 1) & 3);
          gl_lds(Xbb + (size_t)(n0 + row) * C_ + k0 + gs * 8,
                 Bb + ((it - 1) * 512 + (tid & ~63)) * 8);
        }
      }
    } else {
      #pragma unroll
      for (int it = 0; it < 3; it++) {
        const int chunk = it * 256 + tid;
        if (it == 0) {
          const int row = chunk >> 2;
          const int gs = (chunk & 3) ^ ((row >> 1) & 3);
          gl_lds(Wb + (size_t)(m0 + row) * C_ + k0 + gs * 8, Ab + (tid & ~63) * 8);
        } else {
          const int c2 = chunk - 256;
          const int row = c2 >> 2;
          const int gs = (c2 & 3) ^ ((row >> 1) & 3);
          gl_lds(Xbb + (size_t)(n0 + row) * C_ + k0 + gs * 8,
                 Bb + ((it - 1) * 256 + (tid & ~63)) * 8);
        }
      }
    }
  };

  STAGE(0, 0);
  int cur = 0;
  for (int kk = 0; kk < NIT; kk++) {
    if (kk + 1 < NIT) {
      STAGE((cur + 1) % 3, (kk + 1) * 32);
      asm volatile("s_waitcnt vmcnt(3)" ::: "memory");
    } else {
      asm volatile("s_waitcnt vmcnt(0)" ::: "memory");
    }
    __builtin_amdgcn_s_barrier();
    __builtin_amdgcn_sched_barrier(0);
    const unsigned short* As = sm + cur * BUFU;
    const unsigned short* Bs = As + AUSH;
    s16x8 af[MF], bfr[4];
    #pragma unroll
    for (int mf = 0; mf < MF; mf++) {
      const int row = wm * (MF * 16) + mf * 16 + rl;
      const int sl = gq ^ ((row >> 1) & 3);
      af[mf] = *(const s16x8*)&As[row * 32 + sl * 8];
    }
    #pragma unroll
    for (int nf = 0; nf < 4; nf++) {
      const int row = wn * 64 + nf * 16 + rl;
      const int sl = gq ^ ((row >> 1) & 3);
      bfr[nf] = *(const s16x8*)&Bs[row * 32 + sl * 8];
    }
    __builtin_amdgcn_s_setprio(1);
    #pragma unroll
    for (int mf = 0; mf < MF; mf++)
      #pragma unroll
      for (int nf = 0; nf < 4; nf++)
        acc[mf][nf] = __builtin_amdgcn_mfma_f32_16x16x32_bf16(af[mf], bfr[nf],
                                                              acc[mf][nf], 0, 0, 0);
    __builtin_amdgcn_s_setprio(0);
    cur = (cur + 1) % 3;
  }
  __syncthreads();

  if constexpr (MODE == 1) {
    #pragma unroll
    for (int mf = 0; mf < MF; mf++)
      #pragma unroll
      for (int reg = 0; reg < 4; reg++) {
        const int o = m0 + wm * 32 + mf * 16 + gq * 4 + reg;
        const float bsv = bias[o];
        #pragma unroll
        for (int nf = 0; nf < 4; nf++) {
          const int tcol = n0 + wn * 64 + nf * 16 + rl;
          const size_t idx = ((size_t)bz * C_ + o) * T_ + tcol;
          outf[idx] = acc[mf][nf][reg] + bsv + resid[idx];
        }
      }
  } else {
    const bool isV = (m0 >= 2 * C_);
    if (isV) {
      #pragma unroll
      for (int mf = 0; mf < MF; mf++)
        #pragma unroll
        for (int reg = 0; reg < 4; reg++) {
          const int o = m0 + wm * 64 + mf * 16 + gq * 4 + reg;
          const float bsv = bias[o];
          const int od = o - 2 * C_;
          const int hh = od / 80, dd = od % 80;
          #pragma unroll
          for (int nf = 0; nf < 4; nf++) {
            const int t = n0 + wn * 64 + nf * 16 + rl;
            vg[(((size_t)bz * 8 + hh) * 80 + dd) * T_ + t] = f2b(acc[mf][nf][reg] + bsv);
          }
        }
    } else {
      const int which = (m0 >= C_) ? 1 : 0;
      const float osc = which ? 1.f : (0.11180339887498948f * 1.4426950408889634f);
      const int DSTR = which ? 80 : DP_;
      unsigned short* dst0 = which ? kg : qg;
      const int m0eff = m0 - which * C_;
      unsigned short* const L = sm + (wvi & 3) * (64 * 72);
      const int phase = wvi >> 2;
      #pragma unroll
      for (int ph = 0; ph < 2; ph++) {
        if (ph == 1) __syncthreads();
        if (phase == ph) {
          #pragma unroll
          for (int mf = 0; mf < MF; mf++)
            #pragma unroll
            for (int reg = 0; reg < 4; reg++) {
              const int o = m0 + wm * 64 + mf * 16 + gq * 4 + reg;
              const float bsv = bias[o];
              #pragma unroll
              for (int nf = 0; nf < 4; nf++)
                L[(nf * 16 + rl) * 72 + mf * 16 + gq * 4 + reg] =
                    f2b((acc[mf][nf][reg] + bsv) * osc);
            }
          #pragma unroll
          for (int it = 0; it < 8; it++) {
            const int idx = it * 64 + lane;
            const int tl = idx >> 3, seg = idx & 7;
            const uint4 v = *(const uint4*)&L[tl * 72 + seg * 8];
            const int oseg = m0eff + wm * 64 + seg * 8;
            const int hh = oseg / 80, d0 = oseg % 80;
            const int t = n0 + wn * 64 + tl;
            *(uint4*)&dst0[(((size_t)bz * 8 + hh) * T_ + t) * DSTR + d0] = v;
          }
          if (which == 0) {
            const int msBase = m0eff + wm * 64;
            const int h0 = msBase / 80, h1 = (msBase + 63) / 80;
            const uint4 z4 = make_uint4(0u, 0u, 0u, 0u);
            for (int hh2 = h0; hh2 <= h1; hh2++) {
              const int t = n0 + wn * 64 + lane;
              unsigned short* pd = dst0 + (((size_t)bz * 8 + hh2) * T_ + t) * DP_ + 80;
              *(uint4*)pd = z4;
              *(uint4*)(pd + 8) = z4;
            }
          }
        }
      }
    }
  }
}

// ---------------- flash attention: QBLK=64, 4 waves = 2 q-groups x 2 kv-groups ----------------
// Round-16 structure with the SCRATCH-SPILL FIX: the merge epilogue never takes the
// address of a register array (f32x4 values built element-wise) -> m_/l_/o_ stay in VGPRs.
__global__ __launch_bounds__(256, 4) void flash_mfma(
    const unsigned short* __restrict__ Qg, const unsigned short* __restrict__ Kg,
    const unsigned short* __restrict__ Vg, unsigned short* __restrict__ at) {
  __shared__ __align__(16) char arena[40960];
  unsigned short* const Kdb = (unsigned short*)arena;            // 2 x 5120 ush (20,480 B)
  unsigned short* const Vs  = (unsigned short*)(arena + 20480);  // 5120 ush (10,240 B)
  unsigned short* const Ps  = (unsigned short*)(arena + 30720);  // 4 x 1280 ush (10,240 B)
  const int bh = blockIdx.x, qt = blockIdx.y;
  const int b = bh >> 3, h = bh & 7;
  const int tid = threadIdx.x, lane = tid & 63, wvi = tid >> 6;
  const int rl = lane & 15, gq = lane >> 4;
  const int wq = wvi >> 1, wk = wvi & 1;
  const unsigned short* Qt = Qg + ((size_t)bh * T_ + qt * 64) * DP_;
  const unsigned short* Kb = Kg + (size_t)bh * T_ * 80;
  const unsigned short* Vb = Vg + (size_t)bh * 80 * T_;

  {  // stage Q [12 slots][64 rows] into Kdb region (768 chunks = 3*256)
    unsigned short* const qbase = (unsigned short*)Kdb;
    #pragma unroll
    for (int it = 0; it < 3; it++) {
      const int c = it * 256 + tid;
      const int row = c & 63, sl = c >> 6;
      gl_lds(Qt + (size_t)row * DP_ + sl * 8, qbase + (it * 256 + (tid & ~63)) * 8);
    }
  }
  __syncthreads();
  s16x8 qf[2][3];  // Q zero-padded at d>=80: slots 10,11 are zeros
  #pragma unroll
  for (int mfq = 0; mfq < 2; mfq++)
    #pragma unroll
    for (int ks = 0; ks < 3; ks++)
      qf[mfq][ks] = *(const s16x8*)((unsigned short*)Kdb +
                                    ((ks * 4 + gq) * 64 + wq * 32 + mfq * 16 + rl) * 8);
  __syncthreads();

  auto STAGE_K = [&](int buf, int ti) {  // byte-identical to round 14
    const int ko = ti * 64 * 80;
    unsigned short* const KL = Kdb + buf * 5120;
    #pragma unroll
    for (int it = 0; it < 3; it++) {
      if (it < 2 || tid < 128) {
        const int c = it * 256 + tid;
        const int row = c & 63, sl = c >> 6;
        gl_lds(Kb + ko + (size_t)row * 80 + sl * 8, KL + (it * 256 + (tid & ~63)) * 8);
      }
    }
  };
  auto STAGE_V = [&](int ti) {  // byte-identical to round 14
    const int vo = ti * 64;
    #pragma unroll
    for (int it = 0; it < 3; it++) {
      if (it < 2 || tid < 128) {
        const int c = it * 256 + tid;
        const int d = c % 80, s8 = (c / 80) * 8;
        gl_lds(Vb + (size_t)d * T_ + vo + s8, Vs + (it * 256 + (tid & ~63)) * 8);
      }
    }
  };

  const f32x4 zed = {0.f, 0.f, 0.f, 0.f};
  f32x4 o_[2][5];
  float m_[2][4], l_[2][4];  // per (mfq,reg); l_ lane-partial over this lane's keys
  #pragma unroll
  for (int q = 0; q < 2; q++) {
    #pragma unroll
    for (int i = 0; i < 5; i++) o_[q][i] = zed;
    #pragma unroll
    for (int i = 0; i < 4; i++) { m_[q][i] = -1e30f; l_[q][i] = 0.f; }
  }

  STAGE_K(0, 0);
  STAGE_V(0);
  __syncthreads();

  unsigned short* const Pw = Ps + wvi * 1280;  // [32 q][stride 40]
  for (int ti = 0; ti < 16; ti++) {
    const int cur = ti & 1;
    if (ti > 0) STAGE_V(ti);
    if (ti + 1 < 16) STAGE_K(cur ^ 1, ti + 1);
    const unsigned short* Kc = Kdb + cur * 5120;

    // S = Q K^T on this wave's 32 q-rows x 32 keys (keys wk*32 + nf*16 + rl)
    f32x4 s_[2][2];
    #pragma unroll
    for (int q = 0; q < 2; q++)
      #pragma unroll
      for (int nf = 0; nf < 2; nf++) s_[q][nf] = zed;
    __builtin_amdgcn_s_setprio(1);
    #pragma unroll
    for (int nf = 0; nf < 2; nf++)
      #pragma unroll
      for (int ks = 0; ks < 3; ks++) {
        const int sl = (ks < 2) ? (ks * 4 + gq) : (8 + (gq & 1));
        const s16x8 kf = *(const s16x8*)&Kc[(sl * 64 + wk * 32 + nf * 16 + rl) * 8];
        s_[0][nf] = __builtin_amdgcn_mfma_f32_16x16x32_bf16(qf[0][ks], kf, s_[0][nf], 0, 0, 0);
        s_[1][nf] = __builtin_amdgcn_mfma_f32_16x16x32_bf16(qf[1][ks], kf, s_[1][nf], 0, 0, 0);
      }
    __builtin_amdgcn_s_setprio(0);

    // online softmax per (mfq,reg): q-row = wq*32 + mfq*16 + gq*4 + reg
    #pragma unroll
    for (int mfq = 0; mfq < 2; mfq++)
      #pragma unroll
      for (int reg = 0; reg < 4; reg++) {
        const float v0 = s_[mfq][0][reg], v1 = s_[mfq][1][reg];
        const float mold = m_[mfq][reg];
        const float lmx = fmaxf(v0, v1);
        float p0, p1;
        if (__all(lmx <= mold + 8.f)) {
          p0 = __builtin_exp2f(v0 - mold); p1 = __builtin_exp2f(v1 - mold);
          l_[mfq][reg] += p0 + p1;
        } else {
          float mx = lmx;
          mx = fmaxf(mx, __shfl_xor(mx, 1)); mx = fmaxf(mx, __shfl_xor(mx, 2));
          mx = fmaxf(mx, __shfl_xor(mx, 4)); mx = fmaxf(mx, __shfl_xor(mx, 8));
          const float nm = fmaxf(mold, mx);
          const float corr = __builtin_exp2f(mold - nm);
          p0 = __builtin_exp2f(v0 - nm); p1 = __builtin_exp2f(v1 - nm);
          l_[mfq][reg] = l_[mfq][reg] * corr + (p0 + p1);
          m_[mfq][reg] = nm;
          #pragma unroll
          for (int df = 0; df < 5; df++) o_[mfq][df][reg] *= corr;
        }
        unsigned short* const pr = Pw + (mfq * 16 + gq * 4 + reg) * 40;
        pr[rl]      = f2bt(p0);
        pr[16 + rl] = f2bt(p1);
      }
    __syncthreads();  // drains V(ti) + K(ti+1); joins waves

    // O += P V^T (wave's 32 keys: V slots wk*4+gq); vf shared across mfq
    s16x8 pf[2];
    #pragma unroll
    for (int mfq = 0; mfq < 2; mfq++)
      pf[mfq] = *(const s16x8*)&Pw[(mfq * 16 + rl) * 40 + gq * 8];
    __builtin_amdgcn_s_setprio(1);
    #pragma unroll
    for (int df = 0; df < 5; df++) {
      const s16x8 vf = *(const s16x8*)&Vs[((wk * 4 + gq) * 80 + df * 16 + rl) * 8];
      o_[0][df] = __builtin_amdgcn_mfma_f32_16x16x32_bf16(pf[0], vf, o_[0][df], 0, 0, 0);
      o_[1][df] = __builtin_amdgcn_mfma_f32_16x16x32_bf16(pf[1], vf, o_[1][df], 0, 0, 0);
    }
    __builtin_amdgcn_s_setprio(0);
    __syncthreads();  // PV V-reads done before next STAGE_V overwrite
  }

  // ---- merge kv-split partials: wave (wq,1) -> wave (wq,0) ----
  // SCRATCH FIX: never take the address of register arrays; build f32x4 by element.
  __syncthreads();  // all PV done; arena free
  f32x4* const Ob   = (f32x4*)arena;            // 5 x 128 f32x4 = 10,240 B (Kdb region)
  f32x4* const MLb4 = (f32x4*)(arena + 20480);  // 128 x 2 f32x4 = 4,096 B (Vs region)
  const int pid = wq * 64 + lane;               // partner-pair index 0..127
  #pragma unroll
  for (int mfq = 0; mfq < 2; mfq++) {
    if (wk == 1) {
      f32x4 m4, l4;
      #pragma unroll
      for (int reg = 0; reg < 4; reg++) { m4[reg] = m_[mfq][reg]; l4[reg] = l_[mfq][reg]; }
      MLb4[pid * 2]     = m4;
      MLb4[pid * 2 + 1] = l4;
      #pragma unroll
      for (int df = 0; df < 5; df++) Ob[df * 128 + pid] = o_[mfq][df];
    }
    __syncthreads();
    if (wk == 0) {
      const f32x4 m1 = MLb4[pid * 2];
      const f32x4 l1 = MLb4[pid * 2 + 1];
      f32x4 s0, s1;
      #pragma unroll
      for (int reg = 0; reg < 4; reg++) {
        const float nm = fmaxf(m_[mfq][reg], m1[reg]);
        s0[reg] = __builtin_exp2f(m_[mfq][reg] - nm);
        s1[reg] = __builtin_exp2f(m1[reg] - nm);
        l_[mfq][reg] = l_[mfq][reg] * s0[reg] + l1[reg] * s1[reg];
      }
      #pragma unroll
      for (int df = 0; df < 5; df++) {
        const f32x4 o1 = Ob[df * 128 + pid];
        #pragma unroll
        for (int reg = 0; reg < 4; reg++)
          o_[mfq][df][reg] = o_[mfq][df][reg] * s0[reg] + o1[reg] * s1[reg];
      }
    }
    __syncthreads();  // before next mfq reuses the arena
  }

  if (wk == 0) {
    #pragma unroll
    for (int mfq = 0; mfq < 2; mfq++)
      #pragma unroll
      for (int reg = 0; reg < 4; reg++) {
        float l = l_[mfq][reg];  // reduce lane-partials over rl (keys)
        l += __shfl_xor(l, 1); l += __shfl_xor(l, 2);
        l += __shfl_xor(l, 4); l += __shfl_xor(l, 8);
        const float inv = 1.f / l;
        const int t = qt * 64 + wq * 32 + mfq * 16 + gq * 4 + reg;
        #pragma unroll
        for (int df = 0; df < 5; df++)
          at[((size_t)b * T_ + t) * C_ + h * 80 + df * 16 + rl] =
              f2b(o_[mfq][df][reg] * inv);
      }
  }
}

extern "C" void kernel_launch(void* const* d_in, const int* in_sizes, int n_in,
                              void* d_out, int out_size, void* d_ws, size_t ws_size,
                              hipStream_t stream) {
  const float* x      = (const float*)d_in[0];
  const float* norm_w = (const float*)d_in[1];
  const float* norm_b = (const float*)d_in[2];
  const float* qkv_w  = (const float*)d_in[3];
  const float* qkv_b  = (const float*)d_in[4];
  const float* proj_w = (const float*)d_in[5];
  const float* proj_b = (const float*)d_in[6];
  float* out = (float*)d_out;

  char* ws = (char*)d_ws;
  const size_t SEG  = (size_t)B_ * T_ * C_ * 2;          // 10,485,760 B
  const size_t SEGP = (size_t)B_ * NH_ * T_ * DP_ * 2;   // 12,582,912 B (Q only)
  unsigned short* xnt = (unsigned short*)ws;
  unsigned short* Qb  = (unsigned short*)(ws + SEG);
  unsigned short* Kb2 = (unsigned short*)(ws + SEG + SEGP);          // dense 80
  unsigned short* Vb2 = (unsigned short*)(ws + 2 * SEG + SEGP);
  unsigned short* atb = (unsigned short*)(ws + 3 * SEG + SEGP);
  unsigned short* wq  = (unsigned short*)(ws + 4 * SEG + SEGP);
  unsigned short* wp  = (unsigned short*)(ws + 4 * SEG + SEGP + (size_t)3 * C_ * C_ * 2);

  pre_kernel<<<dim3(656), dim3(256), 0, stream>>>(x, norm_w, norm_b, xnt,
                                                  qkv_w, proj_w, wq, wp);
  gemm_mfma<0><<<dim3(15, 4, 8), dim3(512), 0, stream>>>(wq, xnt, qkv_b, nullptr,
                                                         Qb, Kb2, Vb2, nullptr);
  flash_mfma<<<dim3(64, 16), dim3(256), 0, stream>>>(Qb, Kb2, Vb2, atb);
  gemm_mfma<1><<<dim3(10, 8, 8), dim3(256), 0, stream>>>(wp, atb, proj_b, x,
                                                         nullptr, nullptr, nullptr, out);
}

// Round 18
// 135.614 us; speedup vs baseline: 1.3495x; 1.2589x over previous
//
#include <hip/hip_runtime.h>

#define B_   8
#define C_   640
#define T_   1024
#define NH_  8
#define D_   80
#define DP_  96   // padded head dim for Q (12 x 16B slots); K is dense 80

typedef __attribute__((ext_vector_type(8))) short s16x8;
typedef __attribute__((ext_vector_type(4))) float f32x4;

__device__ __forceinline__ unsigned short f2b(float f) {
  unsigned u = __builtin_bit_cast(unsigned, f);
  u += 0x7FFFu + ((u >> 16) & 1u);
  return (unsigned short)(u >> 16);
}
__device__ __forceinline__ unsigned short f2bt(float f) {  // truncate (for P only)
  return (unsigned short)(__builtin_bit_cast(unsigned, f) >> 16);
}

__device__ __forceinline__ void gl_lds(const unsigned short* gp, unsigned short* lp) {
  __builtin_amdgcn_global_load_lds(
      (const __attribute__((address_space(1))) unsigned int*)gp,
      (__attribute__((address_space(3))) unsigned int*)lp, 16, 0, 0);
}

// ---------------- fused GroupNorm (blocks 0..255) + weight conv (blocks 256..655) ----------------
__global__ __launch_bounds__(256) void pre_kernel(
    const float* __restrict__ x, const float* __restrict__ w,
    const float* __restrict__ bias, unsigned short* __restrict__ xnt,
    const float* __restrict__ qw, const float* __restrict__ pw,
    unsigned short* __restrict__ oq, unsigned short* __restrict__ op) {
  const int tid = threadIdx.x;
  if (blockIdx.x >= 256) {  // ---- weight conversion ----
    const int NQ = 3 * C_ * C_ / 4, NP = C_ * C_ / 4;
    int i = (blockIdx.x - 256) * 256 + tid;
    for (; i < NQ + NP; i += 400 * 256) {
      const bool q = i < NQ;
      const float4 v = q ? ((const float4*)qw)[i] : ((const float4*)pw)[i - NQ];
      ushort4 o;
      o.x = f2b(v.x); o.y = f2b(v.y); o.z = f2b(v.z); o.w = f2b(v.w);
      if (q) ((ushort4*)oq)[i] = o; else ((ushort4*)op)[i - NQ] = o;
    }
    return;
  }
  // ---- GroupNorm -> xn^T [b][t][c] bf16 ----
  const int b = blockIdx.x >> 5, g = blockIdx.x & 31;
  const size_t base = ((size_t)b * C_ + g * 20) * T_;
  float s = 0.f, ss = 0.f;
  for (int i = tid; i < 20 * T_; i += 256) {
    const float v = x[base + i];
    s += v; ss += v * v;
  }
  #pragma unroll
  for (int mask = 1; mask < 64; mask <<= 1) {
    s += __shfl_xor(s, mask); ss += __shfl_xor(ss, mask);
  }
  __shared__ float red[2][4];
  if ((tid & 63) == 0) { red[0][tid >> 6] = s; red[1][tid >> 6] = ss; }
  __syncthreads();
  s  = red[0][0] + red[0][1] + red[0][2] + red[0][3];
  ss = red[1][0] + red[1][1] + red[1][2] + red[1][3];
  const float mu   = s * (1.f / 20480.f);
  const float var  = ss * (1.f / 20480.f) - mu * mu;
  const float rstd = rsqrtf(var + 1e-5f);
  float ac[20], bc[20];
  #pragma unroll
  for (int c = 0; c < 20; c++) {
    const float wc = w[g * 20 + c];
    ac[c] = wc * rstd;
    bc[c] = bias[g * 20 + c] - mu * ac[c];
  }
  for (int tc = tid; tc < T_; tc += 256) {
    const size_t xoff = base + tc;
    unsigned short* dst = xnt + ((size_t)b * T_ + tc) * C_ + g * 20;
    #pragma unroll
    for (int j = 0; j < 5; j++) {
      ushort4 o;
      o.x = f2b(x[xoff + (size_t)(j * 4 + 0) * T_] * ac[j * 4 + 0] + bc[j * 4 + 0]);
      o.y = f2b(x[xoff + (size_t)(j * 4 + 1) * T_] * ac[j * 4 + 1] + bc[j * 4 + 1]);
      o.z = f2b(x[xoff + (size_t)(j * 4 + 2) * T_] * ac[j * 4 + 2] + bc[j * 4 + 2]);
      o.w = f2b(x[xoff + (size_t)(j * 4 + 3) * T_] * ac[j * 4 + 3] + bc[j * 4 + 3]);
      *(ushort4*)(dst + j * 4) = o;
    }
  }
}

// ---------------- bf16 MFMA GEMM: 3-buffer rotation, 1 barrier/K-step, counted vmcnt ----------------
// MODE 0: 128x256 tile, 512 thr (8 waves 2x4). A=4096 ush, B=8192 ush, BUFU=12288.
// MODE 1: 64x128 tile, 256 thr (4 waves 2x2). A=2048 ush, B=4096 ush, BUFU=6144.
// Both modes: exactly 3 gl_lds per thread per STAGE -> vmcnt(3) is exact.
// XCD swizzle (T1): bz = linear_block_id & 7.
template <int MODE>
__global__ __launch_bounds__(MODE == 0 ? 512 : 256, 4) void gemm_mfma(
    const unsigned short* __restrict__ Wb, const unsigned short* __restrict__ Xb,
    const float* __restrict__ bias, const float* __restrict__ resid,
    unsigned short* __restrict__ qg, unsigned short* __restrict__ kg,
    unsigned short* __restrict__ vg, float* __restrict__ outf) {
  constexpr int AUSH = MODE == 0 ? 4096 : 2048;   // A-region ushorts (BM*32)
  constexpr int BUFU = MODE == 0 ? 12288 : 6144;  // ushorts per buffer
  constexpr int MF   = MODE == 0 ? 4 : 2;         // row-frags per wave
  constexpr int NIT  = C_ / 32;                   // 20 K-steps
  __shared__ __align__(16) char smem[MODE == 0 ? 73728 : 36864];  // 3 buffers
  unsigned short* const sm = (unsigned short*)smem;
  const int tid = threadIdx.x;
  const int lane = tid & 63, wvi = tid >> 6;
  const int wm = MODE == 0 ? (wvi >> 2) : (wvi >> 1);
  const int wn = MODE == 0 ? (wvi & 3) : (wvi & 1);
  const int rl = lane & 15, gq = lane >> 4;
  const int NM = (MODE == 0) ? 15 : 10;
  const int lid = blockIdx.x + NM * (blockIdx.y + (MODE == 0 ? 4 : 8) * blockIdx.z);
  const int bz = lid & 7;
  const int mn = lid >> 3;
  const int m0 = (mn % NM) * (MODE == 0 ? 128 : 64);
  const int n0 = (mn / NM) * (MODE == 0 ? 256 : 128);
  const unsigned short* Xbb = Xb + (size_t)bz * T_ * C_;

  f32x4 acc[MF][4];
  const f32x4 zed = {0.f, 0.f, 0.f, 0.f};
  #pragma unroll
  for (int i = 0; i < MF; i++)
    #pragma unroll
    for (int j = 0; j < 4; j++) acc[i][j] = zed;

  auto STAGE = [&](int buf, int k0) {
    unsigned short* const Ab = sm + buf * BUFU;
    unsigned short* const Bb = Ab + AUSH;
    if constexpr (MODE == 0) {
      #pragma unroll
      for (int it = 0; it < 3; it++) {
        const int chunk = it * 512 + tid;
        if (chunk < 512) {
          const int row = chunk >> 2;
          const int gs = (chunk & 3) ^ ((row >> 1) & 3);
          gl_lds(Wb + (size_t)(m0 + row) * C_ + k0 + gs * 8, Ab + (tid & ~63) * 8);
        } else {
          const int c2 = chunk - 512;
          const int row = c2 >> 2;
          const int gs = (c2 & 3) ^ ((row >> 1) & 3);
          gl_lds(Xbb + (size_t)(n0 + row) * C_ + k0 + gs * 8,
                 Bb + ((it - 1) * 512 + (tid & ~63)) * 8);
        }
      }
    } else {
      #pragma unroll
      for (int it = 0; it < 3; it++) {
        const int chunk = it * 256 + tid;
        if (it == 0) {
          const int row = chunk >> 2;            // 0..63
          const int gs = (chunk & 3) ^ ((row >> 1) & 3);
          gl_lds(Wb + (size_t)(m0 + row) * C_ + k0 + gs * 8, Ab + (tid & ~63) * 8);
        } else {
          const int c2 = chunk - 256;            // 0..511
          const int row = c2 >> 2;               // 0..127
          const int gs = (c2 & 3) ^ ((row >> 1) & 3);
          gl_lds(Xbb + (size_t)(n0 + row) * C_ + k0 + gs * 8,
                 Bb + ((it - 1) * 256 + (tid & ~63)) * 8);
        }
      }
    }
  };

  STAGE(0, 0);
  int cur = 0;
  for (int kk = 0; kk < NIT; kk++) {
    if (kk + 1 < NIT) {
      STAGE((cur + 1) % 3, (kk + 1) * 32);
      asm volatile("s_waitcnt vmcnt(3)" ::: "memory");  // buf cur's 3 loads (oldest) landed
    } else {
      asm volatile("s_waitcnt vmcnt(0)" ::: "memory");
    }
    __builtin_amdgcn_s_barrier();
    __builtin_amdgcn_sched_barrier(0);
    const unsigned short* As = sm + cur * BUFU;
    const unsigned short* Bs = As + AUSH;
    s16x8 af[MF], bfr[4];
    #pragma unroll
    for (int mf = 0; mf < MF; mf++) {
      const int row = wm * (MF * 16) + mf * 16 + rl;
      const int sl = gq ^ ((row >> 1) & 3);
      af[mf] = *(const s16x8*)&As[row * 32 + sl * 8];
    }
    #pragma unroll
    for (int nf = 0; nf < 4; nf++) {
      const int row = wn * 64 + nf * 16 + rl;
      const int sl = gq ^ ((row >> 1) & 3);
      bfr[nf] = *(const s16x8*)&Bs[row * 32 + sl * 8];
    }
    __builtin_amdgcn_s_setprio(1);
    #pragma unroll
    for (int mf = 0; mf < MF; mf++)
      #pragma unroll
      for (int nf = 0; nf < 4; nf++)
        acc[mf][nf] = __builtin_amdgcn_mfma_f32_16x16x32_bf16(af[mf], bfr[nf],
                                                              acc[mf][nf], 0, 0, 0);
    __builtin_amdgcn_s_setprio(0);
    cur = (cur + 1) % 3;
    // no second barrier: 3-buffer rotation makes next STAGE WAR-safe
  }
  __syncthreads();  // all compute done before epilogue L-overlay reuses smem

  if constexpr (MODE == 1) {
    #pragma unroll
    for (int mf = 0; mf < MF; mf++)
      #pragma unroll
      for (int reg = 0; reg < 4; reg++) {
        const int o = m0 + wm * 32 + mf * 16 + gq * 4 + reg;
        const float bsv = bias[o];
        #pragma unroll
        for (int nf = 0; nf < 4; nf++) {
          const int tcol = n0 + wn * 64 + nf * 16 + rl;
          const size_t idx = ((size_t)bz * C_ + o) * T_ + tcol;
          outf[idx] = acc[mf][nf][reg] + bsv + resid[idx];
        }
      }
  } else {
    const bool isV = (m0 >= 2 * C_);
    if (isV) {
      #pragma unroll
      for (int mf = 0; mf < MF; mf++)
        #pragma unroll
        for (int reg = 0; reg < 4; reg++) {
          const int o = m0 + wm * 64 + mf * 16 + gq * 4 + reg;
          const float bsv = bias[o];
          const int od = o - 2 * C_;
          const int hh = od / 80, dd = od % 80;
          #pragma unroll
          for (int nf = 0; nf < 4; nf++) {
            const int t = n0 + wn * 64 + nf * 16 + rl;
            vg[(((size_t)bz * 8 + hh) * 80 + dd) * T_ + t] = f2b(acc[mf][nf][reg] + bsv);
          }
        }
    } else {
      const int which = (m0 >= C_) ? 1 : 0;  // 0 = Q (96-padded), 1 = K (dense 80)
      const float osc = which ? 1.f : (0.11180339887498948f * 1.4426950408889634f);
      const int DSTR = which ? 80 : DP_;
      unsigned short* dst0 = which ? kg : qg;
      const int m0eff = m0 - which * C_;
      // L buffers: 4 x (64x72) ush (36,864 B overlay), time-shared by wave phase.
      unsigned short* const L = sm + (wvi & 3) * (64 * 72);
      const int phase = wvi >> 2;
      #pragma unroll
      for (int ph = 0; ph < 2; ph++) {
        if (ph == 1) __syncthreads();  // phase-0 waves done with L before reuse
        if (phase == ph) {
          #pragma unroll
          for (int mf = 0; mf < MF; mf++)
            #pragma unroll
            for (int reg = 0; reg < 4; reg++) {
              const int o = m0 + wm * 64 + mf * 16 + gq * 4 + reg;
              const float bsv = bias[o];
              #pragma unroll
              for (int nf = 0; nf < 4; nf++)
                L[(nf * 16 + rl) * 72 + mf * 16 + gq * 4 + reg] =
                    f2b((acc[mf][nf][reg] + bsv) * osc);
            }
          #pragma unroll
          for (int it = 0; it < 8; it++) {
            const int idx = it * 64 + lane;
            const int tl = idx >> 3, seg = idx & 7;
            const uint4 v = *(const uint4*)&L[tl * 72 + seg * 8];
            const int oseg = m0eff + wm * 64 + seg * 8;
            const int hh = oseg / 80, d0 = oseg % 80;
            const int t = n0 + wn * 64 + tl;
            *(uint4*)&dst0[(((size_t)bz * 8 + hh) * T_ + t) * DSTR + d0] = v;
          }
          if (which == 0) {  // zero the d=80..95 pad (Q only)
            const int msBase = m0eff + wm * 64;
            const int h0 = msBase / 80, h1 = (msBase + 63) / 80;
            const uint4 z4 = make_uint4(0u, 0u, 0u, 0u);
            for (int hh2 = h0; hh2 <= h1; hh2++) {
              const int t = n0 + wn * 64 + lane;
              unsigned short* pd = dst0 + (((size_t)bz * 8 + hh2) * T_ + t) * DP_ + 80;
              *(uint4*)pd = z4;
              *(uint4*)(pd + 8) = z4;
            }
          }
        }
      }
    }
  }
}

// ---------------- bf16 MFMA flash attention, QBLK=64, 4 blocks/CU (round-10/14 validated) ----------------
__global__ __launch_bounds__(256, 4) void flash_mfma(
    const unsigned short* __restrict__ Qg, const unsigned short* __restrict__ Kg,
    const unsigned short* __restrict__ Vg, unsigned short* __restrict__ at) {
  __shared__ __align__(16) unsigned short Kdb[2][10 * 64 * 8];  // 20,480 B
  __shared__ __align__(16) unsigned short Vs[8 * 80 * 8];       // 10,240 B
  __shared__ __align__(16) unsigned short Ps[4][16 * 72];       // 9,216 B
  const int bh = blockIdx.x, qt = blockIdx.y;
  const int b = bh >> 3, h = bh & 7;
  const int tid = threadIdx.x, lane = tid & 63, wvi = tid >> 6;
  const int rl = lane & 15, gq = lane >> 4;
  const unsigned short* Qt = Qg + ((size_t)bh * T_ + qt * 64) * DP_;
  const unsigned short* Kb = Kg + (size_t)bh * T_ * 80;
  const unsigned short* Vb = Vg + (size_t)bh * 80 * T_;

  {  // stage Q [12 slots][64 rows] into Kdb region
    unsigned short* const qbase = (unsigned short*)Kdb;
    #pragma unroll
    for (int it = 0; it < 3; it++) {
      const int c = it * 256 + tid;
      const int row = c & 63, sl = c >> 6;
      gl_lds(Qt + (size_t)row * DP_ + sl * 8, qbase + (it * 256 + (tid & ~63)) * 8);
    }
  }
  __syncthreads();
  s16x8 qf[3];  // Q zero-padded at d>=80: qf[2] has zeros for gq>=2
  #pragma unroll
  for (int ks = 0; ks < 3; ks++)
    qf[ks] = *(const s16x8*)((unsigned short*)Kdb +
                             ((ks * 4 + gq) * 64 + wvi * 16 + rl) * 8);
  __syncthreads();

  auto STAGE_K = [&](int buf, int ti) {
    const int ko = ti * 64 * 80;
    #pragma unroll
    for (int it = 0; it < 3; it++) {
      if (it < 2 || tid < 128) {
        const int c = it * 256 + tid;
        const int row = c & 63, sl = c >> 6;
        gl_lds(Kb + ko + (size_t)row * 80 + sl * 8,
               Kdb[buf] + (it * 256 + (tid & ~63)) * 8);
      }
    }
  };
  auto STAGE_V = [&](int ti) {
    const int vo = ti * 64;
    #pragma unroll
    for (int it = 0; it < 3; it++) {
      if (it < 2 || tid < 128) {
        const int c = it * 256 + tid;
        const int d = c % 80, s8 = (c / 80) * 8;
        gl_lds(Vb + (size_t)d * T_ + vo + s8, Vs + (it * 256 + (tid & ~63)) * 8);
      }
    }
  };

  const f32x4 zed = {0.f, 0.f, 0.f, 0.f};
  f32x4 o_[5];
  float m_[4], l_[4];
  #pragma unroll
  for (int i = 0; i < 5; i++) o_[i] = zed;
  #pragma unroll
  for (int i = 0; i < 4; i++) { m_[i] = -1e30f; l_[i] = 0.f; }

  STAGE_K(0, 0);
  STAGE_V(0);
  __syncthreads();

  for (int ti = 0; ti < 16; ti++) {
    const int cur = ti & 1;
    if (ti > 0) STAGE_V(ti);
    if (ti + 1 < 16) STAGE_K(cur ^ 1, ti + 1);
    const unsigned short* Kc = Kdb[cur];

    f32x4 s_[4];
    #pragma unroll
    for (int nf = 0; nf < 4; nf++) s_[nf] = zed;
    __builtin_amdgcn_s_setprio(1);
    #pragma unroll
    for (int nf = 0; nf < 4; nf++)
      #pragma unroll
      for (int ks = 0; ks < 3; ks++) {
        const int sl = (ks < 2) ? (ks * 4 + gq) : (8 + (gq & 1));
        const s16x8 kf = *(const s16x8*)&Kc[(sl * 64 + nf * 16 + rl) * 8];
        s_[nf] = __builtin_amdgcn_mfma_f32_16x16x32_bf16(qf[ks], kf, s_[nf], 0, 0, 0);
      }
    __builtin_amdgcn_s_setprio(0);

    unsigned short* const Pw = Ps[wvi];
    #pragma unroll
    for (int reg = 0; reg < 4; reg++) {
      const float v0 = s_[0][reg], v1 = s_[1][reg];
      const float v2 = s_[2][reg], v3 = s_[3][reg];
      const float mold = m_[reg];
      const float lmx = fmaxf(fmaxf(v0, v1), fmaxf(v2, v3));
      float p0, p1, p2, p3;
      if (__all(lmx <= mold + 8.f)) {
        p0 = __builtin_exp2f(v0 - mold); p1 = __builtin_exp2f(v1 - mold);
        p2 = __builtin_exp2f(v2 - mold); p3 = __builtin_exp2f(v3 - mold);
        l_[reg] += p0 + p1 + p2 + p3;
      } else {
        float mx = lmx;
        mx = fmaxf(mx, __shfl_xor(mx, 1)); mx = fmaxf(mx, __shfl_xor(mx, 2));
        mx = fmaxf(mx, __shfl_xor(mx, 4)); mx = fmaxf(mx, __shfl_xor(mx, 8));
        const float nm = fmaxf(mold, mx);
        const float corr = __builtin_exp2f(mold - nm);
        p0 = __builtin_exp2f(v0 - nm); p1 = __builtin_exp2f(v1 - nm);
        p2 = __builtin_exp2f(v2 - nm); p3 = __builtin_exp2f(v3 - nm);
        l_[reg] = l_[reg] * corr + (p0 + p1 + p2 + p3);
        m_[reg] = nm;
        #pragma unroll
        for (int df = 0; df < 5; df++) o_[df][reg] *= corr;
      }
      unsigned short* const pr = Pw + (gq * 4 + reg) * 72;
      pr[rl]      = f2bt(p0);
      pr[16 + rl] = f2bt(p1);
      pr[32 + rl] = f2bt(p2);
      pr[48 + rl] = f2bt(p3);
    }
    __syncthreads();

    #pragma unroll
    for (int kc = 0; kc < 2; kc++) {
      const s16x8 pf = *(const s16x8*)&Pw[rl * 72 + kc * 32 + gq * 8];
      __builtin_amdgcn_s_setprio(1);
      #pragma unroll
      for (int df = 0; df < 5; df++) {
        const s16x8 vf = *(const s16x8*)&Vs[((kc * 4 + gq) * 80 + df * 16 + rl) * 8];
        o_[df] = __builtin_amdgcn_mfma_f32_16x16x32_bf16(pf, vf, o_[df], 0, 0, 0);
      }
      __builtin_amdgcn_s_setprio(0);
    }
    __syncthreads();
  }

  #pragma unroll
  for (int reg = 0; reg < 4; reg++) {
    float l = l_[reg];
    l += __shfl_xor(l, 1); l += __shfl_xor(l, 2);
    l += __shfl_xor(l, 4); l += __shfl_xor(l, 8);
    const float inv = 1.f / l;
    const int t = qt * 64 + wvi * 16 + gq * 4 + reg;
    #pragma unroll
    for (int df = 0; df < 5; df++)
      at[((size_t)b * T_ + t) * C_ + h * 80 + df * 16 + rl] = f2b(o_[df][reg] * inv);
  }
}

extern "C" void kernel_launch(void* const* d_in, const int* in_sizes, int n_in,
                              void* d_out, int out_size, void* d_ws, size_t ws_size,
                              hipStream_t stream) {
  const float* x      = (const float*)d_in[0];
  const float* norm_w = (const float*)d_in[1];
  const float* norm_b = (const float*)d_in[2];
  const float* qkv_w  = (const float*)d_in[3];
  const float* qkv_b  = (const float*)d_in[4];
  const float* proj_w = (const float*)d_in[5];
  const float* proj_b = (const float*)d_in[6];
  float* out = (float*)d_out;

  char* ws = (char*)d_ws;
  const size_t SEG  = (size_t)B_ * T_ * C_ * 2;          // 10,485,760 B
  const size_t SEGP = (size_t)B_ * NH_ * T_ * DP_ * 2;   // 12,582,912 B (Q only)
  unsigned short* xnt = (unsigned short*)ws;
  unsigned short* Qb  = (unsigned short*)(ws + SEG);
  unsigned short* Kb2 = (unsigned short*)(ws + SEG + SEGP);          // dense 80
  unsigned short* Vb2 = (unsigned short*)(ws + 2 * SEG + SEGP);
  unsigned short* atb = (unsigned short*)(ws + 3 * SEG + SEGP);
  unsigned short* wq  = (unsigned short*)(ws + 4 * SEG + SEGP);
  unsigned short* wp  = (unsigned short*)(ws + 4 * SEG + SEGP + (size_t)3 * C_ * C_ * 2);

  pre_kernel<<<dim3(656), dim3(256), 0, stream>>>(x, norm_w, norm_b, xnt,
                                                  qkv_w, proj_w, wq, wp);
  gemm_mfma<0><<<dim3(15, 4, 8), dim3(512), 0, stream>>>(wq, xnt, qkv_b, nullptr,
                                                         Qb, Kb2, Vb2, nullptr);
  flash_mfma<<<dim3(64, 16), dim3(256), 0, stream>>>(Qb, Kb2, Vb2, atb);
  gemm_mfma<1><<<dim3(10, 8, 8), dim3(256), 0, stream>>>(wp, atb, proj_b, x,
                                                         nullptr, nullptr, nullptr, out);
}

// Round 19
// 117.574 us; speedup vs baseline: 1.5565x; 1.1534x over previous
//
#include <hip/hip_runtime.h>

#define B_   8
#define C_   640
#define T_   1024
#define NH_  8
#define D_   80
#define DP_  96   // padded head dim for Q (12 x 16B slots); K is dense 80

typedef __attribute__((ext_vector_type(8))) short s16x8;
typedef __attribute__((ext_vector_type(4))) float f32x4;

__device__ __forceinline__ unsigned short f2b(float f) {
  unsigned u = __builtin_bit_cast(unsigned, f);
  u += 0x7FFFu + ((u >> 16) & 1u);
  return (unsigned short)(u >> 16);
}
__device__ __forceinline__ unsigned short f2bt(float f) {  // truncate (for P only)
  return (unsigned short)(__builtin_bit_cast(unsigned, f) >> 16);
}

__device__ __forceinline__ void gl_lds(const unsigned short* gp, unsigned short* lp) {
  __builtin_amdgcn_global_load_lds(
      (const __attribute__((address_space(1))) unsigned int*)gp,
      (__attribute__((address_space(3))) unsigned int*)lp, 16, 0, 0);
}

// ---------------- fused GroupNorm (blocks 0..255) + weight conv (blocks 256..655) ----------------
// GN is SINGLE-PASS: x cached in registers (xs[4][20], all indices compile-time constant),
// halving gn's HBM read traffic (67 -> 33.5 MB).
__global__ __launch_bounds__(256) void pre_kernel(
    const float* __restrict__ x, const float* __restrict__ w,
    const float* __restrict__ bias, unsigned short* __restrict__ xnt,
    const float* __restrict__ qw, const float* __restrict__ pw,
    unsigned short* __restrict__ oq, unsigned short* __restrict__ op) {
  const int tid = threadIdx.x;
  if (blockIdx.x >= 256) {  // ---- weight conversion ----
    const int NQ = 3 * C_ * C_ / 4, NP = C_ * C_ / 4;
    int i = (blockIdx.x - 256) * 256 + tid;
    for (; i < NQ + NP; i += 400 * 256) {
      const bool q = i < NQ;
      const float4 v = q ? ((const float4*)qw)[i] : ((const float4*)pw)[i - NQ];
      ushort4 o;
      o.x = f2b(v.x); o.y = f2b(v.y); o.z = f2b(v.z); o.w = f2b(v.w);
      if (q) ((ushort4*)oq)[i] = o; else ((ushort4*)op)[i - NQ] = o;
    }
    return;
  }
  // ---- GroupNorm -> xn^T [b][t][c] bf16 (single-pass, register-cached) ----
  const int b = blockIdx.x >> 5, g = blockIdx.x & 31;
  const size_t base = ((size_t)b * C_ + g * 20) * T_;
  float xs[4][20];
  float s = 0.f, ss = 0.f;
  #pragma unroll
  for (int u = 0; u < 4; u++) {
    const int tc = tid + u * 256;
    #pragma unroll
    for (int c = 0; c < 20; c++) {
      const float v = x[base + (size_t)c * T_ + tc];
      xs[u][c] = v;
      s += v; ss += v * v;
    }
  }
  #pragma unroll
  for (int mask = 1; mask < 64; mask <<= 1) {
    s += __shfl_xor(s, mask); ss += __shfl_xor(ss, mask);
  }
  __shared__ float red[2][4];
  if ((tid & 63) == 0) { red[0][tid >> 6] = s; red[1][tid >> 6] = ss; }
  __syncthreads();
  s  = red[0][0] + red[0][1] + red[0][2] + red[0][3];
  ss = red[1][0] + red[1][1] + red[1][2] + red[1][3];
  const float mu   = s * (1.f / 20480.f);
  const float var  = ss * (1.f / 20480.f) - mu * mu;
  const float rstd = rsqrtf(var + 1e-5f);
  #pragma unroll
  for (int u = 0; u < 4; u++) {
    const int tc = tid + u * 256;
    unsigned short* dst = xnt + ((size_t)b * T_ + tc) * C_ + g * 20;
    #pragma unroll
    for (int j = 0; j < 5; j++) {
      ushort4 o;
      #pragma unroll
      for (int e = 0; e < 4; e++) {
        const int c = j * 4 + e;
        const float a  = w[g * 20 + c] * rstd;          // g uniform -> scalar load
        const float bc = bias[g * 20 + c] - mu * a;
        const unsigned short r = f2b(xs[u][c] * a + bc);
        if (e == 0) o.x = r; else if (e == 1) o.y = r;
        else if (e == 2) o.z = r; else o.w = r;
      }
      *(ushort4*)(dst + j * 4) = o;
    }
  }
}

// ---------------- bf16 MFMA GEMM: 3-buffer rotation, 1 barrier/K-step, counted vmcnt ----------------
// MODE 0: 128x256 tile, 512 thr (8 waves 2x4). A=4096 ush, B=8192 ush, BUFU=12288.
// MODE 1: 64x128 tile, 256 thr (4 waves 2x2). A=2048 ush, B=4096 ush, BUFU=6144.
// Both modes: exactly 3 gl_lds per thread per STAGE -> vmcnt(3) is exact.
// XCD swizzle (T1): bz = linear_block_id & 7.
template <int MODE>
__global__ __launch_bounds__(MODE == 0 ? 512 : 256, 4) void gemm_mfma(
    const unsigned short* __restrict__ Wb, const unsigned short* __restrict__ Xb,
    const float* __restrict__ bias, const float* __restrict__ resid,
    unsigned short* __restrict__ qg, unsigned short* __restrict__ kg,
    unsigned short* __restrict__ vg, float* __restrict__ outf) {
  constexpr int AUSH = MODE == 0 ? 4096 : 2048;   // A-region ushorts (BM*32)
  constexpr int BUFU = MODE == 0 ? 12288 : 6144;  // ushorts per buffer
  constexpr int MF   = MODE == 0 ? 4 : 2;         // row-frags per wave
  constexpr int NIT  = C_ / 32;                   // 20 K-steps
  __shared__ __align__(16) char smem[MODE == 0 ? 73728 : 36864];  // 3 buffers
  unsigned short* const sm = (unsigned short*)smem;
  const int tid = threadIdx.x;
  const int lane = tid & 63, wvi = tid >> 6;
  const int wm = MODE == 0 ? (wvi >> 2) : (wvi >> 1);
  const int wn = MODE == 0 ? (wvi & 3) : (wvi & 1);
  const int rl = lane & 15, gq = lane >> 4;
  const int NM = (MODE == 0) ? 15 : 10;
  const int lid = blockIdx.x + NM * (blockIdx.y + (MODE == 0 ? 4 : 8) * blockIdx.z);
  const int bz = lid & 7;
  const int mn = lid >> 3;
  const int m0 = (mn % NM) * (MODE == 0 ? 128 : 64);
  const int n0 = (mn / NM) * (MODE == 0 ? 256 : 128);
  const unsigned short* Xbb = Xb + (size_t)bz * T_ * C_;

  f32x4 acc[MF][4];
  const f32x4 zed = {0.f, 0.f, 0.f, 0.f};
  #pragma unroll
  for (int i = 0; i < MF; i++)
    #pragma unroll
    for (int j = 0; j < 4; j++) acc[i][j] = zed;

  auto STAGE = [&](int buf, int k0) {
    unsigned short* const Ab = sm + buf * BUFU;
    unsigned short* const Bb = Ab + AUSH;
    if constexpr (MODE == 0) {
      #pragma unroll
      for (int it = 0; it < 3; it++) {
        const int chunk = it * 512 + tid;
        if (chunk < 512) {
          const int row = chunk >> 2;
          const int gs = (chunk & 3) ^ ((row >> 1) & 3);
          gl_lds(Wb + (size_t)(m0 + row) * C_ + k0 + gs * 8, Ab + (tid & ~63) * 8);
        } else {
          const int c2 = chunk - 512;
          const int row = c2 >> 2;
          const int gs = (c2 & 3) ^ ((row >> 1) & 3);
          gl_lds(Xbb + (size_t)(n0 + row) * C_ + k0 + gs * 8,
                 Bb + ((it - 1) * 512 + (tid & ~63)) * 8);
        }
      }
    } else {
      #pragma unroll
      for (int it = 0; it < 3; it++) {
        const int chunk = it * 256 + tid;
        if (it == 0) {
          const int row = chunk >> 2;            // 0..63
          const int gs = (chunk & 3) ^ ((row >> 1) & 3);
          gl_lds(Wb + (size_t)(m0 + row) * C_ + k0 + gs * 8, Ab + (tid & ~63) * 8);
        } else {
          const int c2 = chunk - 256;            // 0..511
          const int row = c2 >> 2;               // 0..127
          const int gs = (c2 & 3) ^ ((row >> 1) & 3);
          gl_lds(Xbb + (size_t)(n0 + row) * C_ + k0 + gs * 8,
                 Bb + ((it - 1) * 256 + (tid & ~63)) * 8);
        }
      }
    }
  };

  STAGE(0, 0);
  int cur = 0;
  for (int kk = 0; kk < NIT; kk++) {
    if (kk + 1 < NIT) {
      STAGE((cur + 1) % 3, (kk + 1) * 32);
      asm volatile("s_waitcnt vmcnt(3)" ::: "memory");  // buf cur's 3 loads (oldest) landed
    } else {
      asm volatile("s_waitcnt vmcnt(0)" ::: "memory");
    }
    __builtin_amdgcn_s_barrier();
    __builtin_amdgcn_sched_barrier(0);
    const unsigned short* As = sm + cur * BUFU;
    const unsigned short* Bs = As + AUSH;
    s16x8 af[MF], bfr[4];
    #pragma unroll
    for (int mf = 0; mf < MF; mf++) {
      const int row = wm * (MF * 16) + mf * 16 + rl;
      const int sl = gq ^ ((row >> 1) & 3);
      af[mf] = *(const s16x8*)&As[row * 32 + sl * 8];
    }
    #pragma unroll
    for (int nf = 0; nf < 4; nf++) {
      const int row = wn * 64 + nf * 16 + rl;
      const int sl = gq ^ ((row >> 1) & 3);
      bfr[nf] = *(const s16x8*)&Bs[row * 32 + sl * 8];
    }
    __builtin_amdgcn_s_setprio(1);
    #pragma unroll
    for (int mf = 0; mf < MF; mf++)
      #pragma unroll
      for (int nf = 0; nf < 4; nf++)
        acc[mf][nf] = __builtin_amdgcn_mfma_f32_16x16x32_bf16(af[mf], bfr[nf],
                                                              acc[mf][nf], 0, 0, 0);
    __builtin_amdgcn_s_setprio(0);
    cur = (cur + 1) % 3;
    // no second barrier: 3-buffer rotation makes next STAGE WAR-safe
  }
  __syncthreads();  // all compute done before epilogue L-overlay reuses smem

  if constexpr (MODE == 1) {
    #pragma unroll
    for (int mf = 0; mf < MF; mf++)
      #pragma unroll
      for (int reg = 0; reg < 4; reg++) {
        const int o = m0 + wm * 32 + mf * 16 + gq * 4 + reg;
        const float bsv = bias[o];
        #pragma unroll
        for (int nf = 0; nf < 4; nf++) {
          const int tcol = n0 + wn * 64 + nf * 16 + rl;
          const size_t idx = ((size_t)bz * C_ + o) * T_ + tcol;
          outf[idx] = acc[mf][nf][reg] + bsv + resid[idx];
        }
      }
  } else {
    const bool isV = (m0 >= 2 * C_);
    if (isV) {
      #pragma unroll
      for (int mf = 0; mf < MF; mf++)
        #pragma unroll
        for (int reg = 0; reg < 4; reg++) {
          const int o = m0 + wm * 64 + mf * 16 + gq * 4 + reg;
          const float bsv = bias[o];
          const int od = o - 2 * C_;
          const int hh = od / 80, dd = od % 80;
          #pragma unroll
          for (int nf = 0; nf < 4; nf++) {
            const int t = n0 + wn * 64 + nf * 16 + rl;
            vg[(((size_t)bz * 8 + hh) * 80 + dd) * T_ + t] = f2b(acc[mf][nf][reg] + bsv);
          }
        }
    } else {
      const int which = (m0 >= C_) ? 1 : 0;  // 0 = Q (96-padded), 1 = K (dense 80)
      const float osc = which ? 1.f : (0.11180339887498948f * 1.4426950408889634f);
      const int DSTR = which ? 80 : DP_;
      unsigned short* dst0 = which ? kg : qg;
      const int m0eff = m0 - which * C_;
      // L buffers: 4 x (64x72) ush (36,864 B overlay), time-shared by wave phase.
      unsigned short* const L = sm + (wvi & 3) * (64 * 72);
      const int phase = wvi >> 2;
      #pragma unroll
      for (int ph = 0; ph < 2; ph++) {
        if (ph == 1) __syncthreads();  // phase-0 waves done with L before reuse
        if (phase == ph) {
          #pragma unroll
          for (int mf = 0; mf < MF; mf++)
            #pragma unroll
            for (int reg = 0; reg < 4; reg++) {
              const int o = m0 + wm * 64 + mf * 16 + gq * 4 + reg;
              const float bsv = bias[o];
              #pragma unroll
              for (int nf = 0; nf < 4; nf++)
                L[(nf * 16 + rl) * 72 + mf * 16 + gq * 4 + reg] =
                    f2b((acc[mf][nf][reg] + bsv) * osc);
            }
          #pragma unroll
          for (int it = 0; it < 8; it++) {
            const int idx = it * 64 + lane;
            const int tl = idx >> 3, seg = idx & 7;
            const uint4 v = *(const uint4*)&L[tl * 72 + seg * 8];
            const int oseg = m0eff + wm * 64 + seg * 8;
            const int hh = oseg / 80, d0 = oseg % 80;
            const int t = n0 + wn * 64 + tl;
            *(uint4*)&dst0[(((size_t)bz * 8 + hh) * T_ + t) * DSTR + d0] = v;
          }
          if (which == 0) {  // zero the d=80..95 pad (Q only)
            const int msBase = m0eff + wm * 64;
            const int h0 = msBase / 80, h1 = (msBase + 63) / 80;
            const uint4 z4 = make_uint4(0u, 0u, 0u, 0u);
            for (int hh2 = h0; hh2 <= h1; hh2++) {
              const int t = n0 + wn * 64 + lane;
              unsigned short* pd = dst0 + (((size_t)bz * 8 + hh2) * T_ + t) * DP_ + 80;
              *(uint4*)pd = z4;
              *(uint4*)(pd + 8) = z4;
            }
          }
        }
      }
    }
  }
}

// ---------------- bf16 MFMA flash attention, QBLK=64, 4 blocks/CU (round-10/14 validated) ----------------
__global__ __launch_bounds__(256, 4) void flash_mfma(
    const unsigned short* __restrict__ Qg, const unsigned short* __restrict__ Kg,
    const unsigned short* __restrict__ Vg, unsigned short* __restrict__ at) {
  __shared__ __align__(16) unsigned short Kdb[2][10 * 64 * 8];  // 20,480 B
  __shared__ __align__(16) unsigned short Vs[8 * 80 * 8];       // 10,240 B
  __shared__ __align__(16) unsigned short Ps[4][16 * 72];       // 9,216 B
  const int bh = blockIdx.x, qt = blockIdx.y;
  const int b = bh >> 3, h = bh & 7;
  const int tid = threadIdx.x, lane = tid & 63, wvi = tid >> 6;
  const int rl = lane & 15, gq = lane >> 4;
  const unsigned short* Qt = Qg + ((size_t)bh * T_ + qt * 64) * DP_;
  const unsigned short* Kb = Kg + (size_t)bh * T_ * 80;
  const unsigned short* Vb = Vg + (size_t)bh * 80 * T_;

  {  // stage Q [12 slots][64 rows] into Kdb region
    unsigned short* const qbase = (unsigned short*)Kdb;
    #pragma unroll
    for (int it = 0; it < 3; it++) {
      const int c = it * 256 + tid;
      const int row = c & 63, sl = c >> 6;
      gl_lds(Qt + (size_t)row * DP_ + sl * 8, qbase + (it * 256 + (tid & ~63)) * 8);
    }
  }
  __syncthreads();
  s16x8 qf[3];  // Q zero-padded at d>=80: qf[2] has zeros for gq>=2
  #pragma unroll
  for (int ks = 0; ks < 3; ks++)
    qf[ks] = *(const s16x8*)((unsigned short*)Kdb +
                             ((ks * 4 + gq) * 64 + wvi * 16 + rl) * 8);
  __syncthreads();

  auto STAGE_K = [&](int buf, int ti) {
    const int ko = ti * 64 * 80;
    #pragma unroll
    for (int it = 0; it < 3; it++) {
      if (it < 2 || tid < 128) {
        const int c = it * 256 + tid;
        const int row = c & 63, sl = c >> 6;
        gl_lds(Kb + ko + (size_t)row * 80 + sl * 8,
               Kdb[buf] + (it * 256 + (tid & ~63)) * 8);
      }
    }
  };
  auto STAGE_V = [&](int ti) {
    const int vo = ti * 64;
    #pragma unroll
    for (int it = 0; it < 3; it++) {
      if (it < 2 || tid < 128) {
        const int c = it * 256 + tid;
        const int d = c % 80, s8 = (c / 80) * 8;
        gl_lds(Vb + (size_t)d * T_ + vo + s8, Vs + (it * 256 + (tid & ~63)) * 8);
      }
    }
  };

  const f32x4 zed = {0.f, 0.f, 0.f, 0.f};
  f32x4 o_[5];
  float m_[4], l_[4];
  #pragma unroll
  for (int i = 0; i < 5; i++) o_[i] = zed;
  #pragma unroll
  for (int i = 0; i < 4; i++) { m_[i] = -1e30f; l_[i] = 0.f; }

  STAGE_K(0, 0);
  STAGE_V(0);
  __syncthreads();

  for (int ti = 0; ti < 16; ti++) {
    const int cur = ti & 1;
    if (ti > 0) STAGE_V(ti);
    if (ti + 1 < 16) STAGE_K(cur ^ 1, ti + 1);
    const unsigned short* Kc = Kdb[cur];

    f32x4 s_[4];
    #pragma unroll
    for (int nf = 0; nf < 4; nf++) s_[nf] = zed;
    __builtin_amdgcn_s_setprio(1);
    #pragma unroll
    for (int nf = 0; nf < 4; nf++)
      #pragma unroll
      for (int ks = 0; ks < 3; ks++) {
        const int sl = (ks < 2) ? (ks * 4 + gq) : (8 + (gq & 1));
        const s16x8 kf = *(const s16x8*)&Kc[(sl * 64 + nf * 16 + rl) * 8];
        s_[nf] = __builtin_amdgcn_mfma_f32_16x16x32_bf16(qf[ks], kf, s_[nf], 0, 0, 0);
      }
    __builtin_amdgcn_s_setprio(0);

    unsigned short* const Pw = Ps[wvi];
    #pragma unroll
    for (int reg = 0; reg < 4; reg++) {
      const float v0 = s_[0][reg], v1 = s_[1][reg];
      const float v2 = s_[2][reg], v3 = s_[3][reg];
      const float mold = m_[reg];
      const float lmx = fmaxf(fmaxf(v0, v1), fmaxf(v2, v3));
      float p0, p1, p2, p3;
      if (__all(lmx <= mold + 8.f)) {
        p0 = __builtin_exp2f(v0 - mold); p1 = __builtin_exp2f(v1 - mold);
        p2 = __builtin_exp2f(v2 - mold); p3 = __builtin_exp2f(v3 - mold);
        l_[reg] += p0 + p1 + p2 + p3;
      } else {
        float mx = lmx;
        mx = fmaxf(mx, __shfl_xor(mx, 1)); mx = fmaxf(mx, __shfl_xor(mx, 2));
        mx = fmaxf(mx, __shfl_xor(mx, 4)); mx = fmaxf(mx, __shfl_xor(mx, 8));
        const float nm = fmaxf(mold, mx);
        const float corr = __builtin_exp2f(mold - nm);
        p0 = __builtin_exp2f(v0 - nm); p1 = __builtin_exp2f(v1 - nm);
        p2 = __builtin_exp2f(v2 - nm); p3 = __builtin_exp2f(v3 - nm);
        l_[reg] = l_[reg] * corr + (p0 + p1 + p2 + p3);
        m_[reg] = nm;
        #pragma unroll
        for (int df = 0; df < 5; df++) o_[df][reg] *= corr;
      }
      unsigned short* const pr = Pw + (gq * 4 + reg) * 72;
      pr[rl]      = f2bt(p0);
      pr[16 + rl] = f2bt(p1);
      pr[32 + rl] = f2bt(p2);
      pr[48 + rl] = f2bt(p3);
    }
    __syncthreads();

    #pragma unroll
    for (int kc = 0; kc < 2; kc++) {
      const s16x8 pf = *(const s16x8*)&Pw[rl * 72 + kc * 32 + gq * 8];
      __builtin_amdgcn_s_setprio(1);
      #pragma unroll
      for (int df = 0; df < 5; df++) {
        const s16x8 vf = *(const s16x8*)&Vs[((kc * 4 + gq) * 80 + df * 16 + rl) * 8];
        o_[df] = __builtin_amdgcn_mfma_f32_16x16x32_bf16(pf, vf, o_[df], 0, 0, 0);
      }
      __builtin_amdgcn_s_setprio(0);
    }
    __syncthreads();
  }

  #pragma unroll
  for (int reg = 0; reg < 4; reg++) {
    float l = l_[reg];
    l += __shfl_xor(l, 1); l += __shfl_xor(l, 2);
    l += __shfl_xor(l, 4); l += __shfl_xor(l, 8);
    const float inv = 1.f / l;
    const int t = qt * 64 + wvi * 16 + gq * 4 + reg;
    #pragma unroll
    for (int df = 0; df < 5; df++)
      at[((size_t)b * T_ + t) * C_ + h * 80 + df * 16 + rl] = f2b(o_[df][reg] * inv);
  }
}

extern "C" void kernel_launch(void* const* d_in, const int* in_sizes, int n_in,
                              void* d_out, int out_size, void* d_ws, size_t ws_size,
                              hipStream_t stream) {
  const float* x      = (const float*)d_in[0];
  const float* norm_w = (const float*)d_in[1];
  const float* norm_b = (const float*)d_in[2];
  const float* qkv_w  = (const float*)d_in[3];
  const float* qkv_b  = (const float*)d_in[4];
  const float* proj_w = (const float*)d_in[5];
  const float* proj_b = (const float*)d_in[6];
  float* out = (float*)d_out;

  char* ws = (char*)d_ws;
  const size_t SEG  = (size_t)B_ * T_ * C_ * 2;          // 10,485,760 B
  const size_t SEGP = (size_t)B_ * NH_ * T_ * DP_ * 2;   // 12,582,912 B (Q only)
  unsigned short* xnt = (unsigned short*)ws;
  unsigned short* Qb  = (unsigned short*)(ws + SEG);
  unsigned short* Kb2 = (unsigned short*)(ws + SEG + SEGP);          // dense 80
  unsigned short* Vb2 = (unsigned short*)(ws + 2 * SEG + SEGP);
  unsigned short* atb = (unsigned short*)(ws + 3 * SEG + SEGP);
  unsigned short* wq  = (unsigned short*)(ws + 4 * SEG + SEGP);
  unsigned short* wp  = (unsigned short*)(ws + 4 * SEG + SEGP + (size_t)3 * C_ * C_ * 2);

  pre_kernel<<<dim3(656), dim3(256), 0, stream>>>(x, norm_w, norm_b, xnt,
                                                  qkv_w, proj_w, wq, wp);
  gemm_mfma<0><<<dim3(15, 4, 8), dim3(512), 0, stream>>>(wq, xnt, qkv_b, nullptr,
                                                         Qb, Kb2, Vb2, nullptr);
  flash_mfma<<<dim3(64, 16), dim3(256), 0, stream>>>(Qb, Kb2, Vb2, atb);
  gemm_mfma<1><<<dim3(10, 8, 8), dim3(256), 0, stream>>>(wp, atb, proj_b, x,
                                                         nullptr, nullptr, nullptr, out);
}